// Round 3
// baseline (1100.529 us; speedup 1.0000x reference)
//
#include <hip/hip_runtime.h>
#include <hip/hip_bf16.h>

// HINGE_56985626083396 — fused embedding-conv-BN-min-FC forward on MI355X.
//
// Round-12: two-pass minimum-crossing restructure. Governing law from
// r8-r11 counters: dur ~= FETCH / 0.4 TB/s on the scattered-gather path.
// r11's merge FAILED (FETCH 686MB, WRITE 805MB: NT-store write amplification
// + interleave thrash). This round reaches the algorithmic minimum of TWO
// table crossings, each at HALF width:
//  (1) Eliminate Hbuf and min1: windows 2..5 share H additively and m2 =
//      min_k relu(a_k(H+t_k)+c_k) is computed incrementally in registers
//      (H bf16-packed, one t_k GEMM at a time); m1 (windows 0,1) lives in
//      block-local LDS. No 32MB intermediates, no extra crossings.
//  (2) Workspace (proven >= 69.1MB) now fits bf16 tables (51.2MB): one
//      streaming cvt (~30us at full BW), then all gathers move half the
//      bytes and the 51MB footprint is L3-retainable.
// passA: merged G1-stats (K=512, RPB2) + T-stats (K=1280 full win2, RPB4),
//        block-local LDS stats, one global flush. 512 blocks, 2/CU.
// passB: merged G1-min -> LDS m1 + H (K=768) -> regs + 4x t_k (K=512) ->
//        running m2 + fused min/dot(fcw)/reduce -> outacc. 512 blocks.
// conv biases skipped: BN mean-subtraction cancels them exactly.
// Numerics identical to r10's proven path (same bf16 staging values).

typedef __hip_bfloat16 bf16;
typedef short bf16x8 __attribute__((ext_vector_type(8)));   // 8 bf16 in 4 VGPRs
typedef float f32x4 __attribute__((ext_vector_type(4)));

#define BATCH 32768

__device__ __forceinline__ unsigned short f2b(float f) {
    union { float f; unsigned u; } v; v.f = f;
    unsigned r = v.u + 0x7fffu + ((v.u >> 16) & 1u);   // round-to-nearest-even
    return (unsigned short)(r >> 16);
}

__device__ __forceinline__ float b2f(unsigned short u) {
    union { unsigned x; float f; } v; v.x = ((unsigned)u) << 16;
    return v.f;
}

__global__ __launch_bounds__(256)
void cvt_kernel(const float* __restrict__ src, unsigned short* __restrict__ dst, int n4)
{
    int i = blockIdx.x * 256 + threadIdx.x;
    if (i >= n4) return;
    float4 v = ((const float4*)src)[i];
    ushort4 h;
    h.x = f2b(v.x); h.y = f2b(v.y); h.z = f2b(v.z); h.w = f2b(v.w);
    ((ushort4*)dst)[i] = h;
}

// Row->embedding-index selection. PICK: 0=G1(RPB2 [fv_kk|fr0]), 1=T-full
// (RPB4 [fv0|fr0|fv1|kr_kk|kv_kk]), 2=H(RPB1 [fv0|fr0|fv1]), 3=Tk(RPB1
// [kr_tk|kv_tk]). bloc = batch-row offset of this subtile within xsh.
template<int PICK>
__device__ __forceinline__ void pickfn(const int* xsh, int row, int seg,
                                       int bloc, int tk, int& idx, int& isRole)
{
    if constexpr (PICK == 0) {
        int bl = (row >> 1) + bloc, kk = row & 1;
        if (seg == 0) { idx = xsh[bl * 12 + 2 * kk + 1]; isRole = 0; }
        else          { idx = xsh[bl * 12 + 0];          isRole = 1; }
    } else if constexpr (PICK == 1) {
        int bl = (row >> 2) + bloc, kk = row & 3;
        switch (seg) {
            case 0:  idx = xsh[bl * 12 + 1];          isRole = 0; break;
            case 1:  idx = xsh[bl * 12 + 0];          isRole = 1; break;
            case 2:  idx = xsh[bl * 12 + 3];          isRole = 0; break;
            case 3:  idx = xsh[bl * 12 + 2 * kk + 4]; isRole = 1; break;
            default: idx = xsh[bl * 12 + 2 * kk + 5]; isRole = 0; break;
        }
    } else if constexpr (PICK == 2) {
        if      (seg == 0) { idx = xsh[row * 12 + 1]; isRole = 0; }
        else if (seg == 1) { idx = xsh[row * 12 + 0]; isRole = 1; }
        else               { idx = xsh[row * 12 + 3]; isRole = 0; }
    } else {
        if (seg == 0) { idx = xsh[row * 12 + 2 * tk + 4]; isRole = 1; }
        else          { idx = xsh[row * 12 + 2 * tk + 5]; isRole = 0; }
    }
}

// One sub-GEMM: acc[128x256 tile] = A(gathered bf16 rows) . W[n_base:+256,
// KWOFF:KWOFF+KLEN]^T. Block 512 thr, 8 waves 2x4, wave tile 64x64, BK=64.
template<int KLEN, int KSTR, int KWOFF, int PICK>
__device__ __forceinline__ void gemm_acc(
    const bf16* __restrict__ embR, const bf16* __restrict__ embV,
    const bf16* __restrict__ W, short* Ash, short* Bsh, const int* xsh,
    int n_base, int bloc, int tk, f32x4 (&acc)[4][4])
{
    const int tid  = threadIdx.x;
    const int lane = tid & 63;
    const int wv   = tid >> 6;
    const int wmb  = (wv >> 2) * 64;
    const int wnb  = (wv & 3) * 64;
    const int quad = lane >> 4;
    const int l16  = lane & 15;

    #pragma unroll
    for (int i = 0; i < 4; ++i)
        #pragma unroll
        for (int j = 0; j < 4; ++j)
            acc[i][j] = (f32x4){0.f, 0.f, 0.f, 0.f};

    constexpr int NCH = KLEN / 64;
    for (int ch = 0; ch < NCH; ++ch) {
        const int k0  = ch * 64;
        const int seg = k0 >> 8;
        const int so8 = (k0 & 255) >> 3;
        // ---- stage A: 128 rows x 64 k (bf16 tables, 2 x uint4/thread) ----
        #pragma unroll
        for (int i = 0; i < 2; ++i) {
            int flat = tid + i * 512;               // 0..1023
            int row  = flat >> 3;
            int off8 = flat & 7;
            int idx, isRole;
            pickfn<PICK>(xsh, row, seg, bloc, tk, idx, isRole);
            const bf16* tab = isRole ? embR : embV;
            uint4 v = ((const uint4*)(tab + (size_t)idx * 256))[so8 + off8];
            *(uint4*)&Ash[row * 72 + off8 * 8] = v;
        }
        // ---- stage B: W rows f in [n_base,+256), k-chunk ----
        #pragma unroll
        for (int i = 0; i < 4; ++i) {
            int flat = tid + i * 512;               // 0..2047
            int fr   = flat >> 3;
            int off8 = flat & 7;
            uint4 v = ((const uint4*)(W + (size_t)(n_base + fr) * KSTR + KWOFF + k0))[off8];
            *(uint4*)&Bsh[fr * 72 + off8 * 8] = v;
        }
        __syncthreads();
        #pragma unroll
        for (int ks = 0; ks < 64; ks += 32) {
            bf16x8 af[4], bf_[4];
            #pragma unroll
            for (int t = 0; t < 4; ++t)
                af[t]  = *(const bf16x8*)&Ash[(wmb + t * 16 + l16) * 72 + ks + quad * 8];
            #pragma unroll
            for (int t = 0; t < 4; ++t)
                bf_[t] = *(const bf16x8*)&Bsh[(wnb + t * 16 + l16) * 72 + ks + quad * 8];
            #pragma unroll
            for (int i = 0; i < 4; ++i)
                #pragma unroll
                for (int j = 0; j < 4; ++j)
                    acc[i][j] = __builtin_amdgcn_mfma_f32_16x16x32_bf16(
                        af[i], bf_[j], acc[i][j], 0, 0, 0);
        }
        __syncthreads();
    }
}

// Pass A: per (128-batch, 256-f) block, all 6 window sums/sumsqs.
// C/D layout: f(col) = l16, m(row) = quad*4 + reg.
__global__ __launch_bounds__(512, 4)
void passA_kernel(const int* __restrict__ x, const bf16* __restrict__ embR,
                  const bf16* __restrict__ embV, const bf16* __restrict__ W1b,
                  const bf16* __restrict__ W2b, float* __restrict__ accum)
{
    __shared__ __align__(16) short Ash[128 * 72];
    __shared__ __align__(16) short Bsh[256 * 72];
    __shared__ int   xsh[128 * 12];
    __shared__ float red[2 * 6 * 256];              // [s|q][kw][fl]

    const int tid = threadIdx.x;
    const int lin = blockIdx.x;
    const int grp = (lin >> 4) * 8 + (lin & 7);     // 2 n-siblings same XCD
    const int nt  = (lin >> 3) & 1;
    const int n_base = nt * 256;

    for (int i = tid; i < 1536; i += 512) xsh[i] = x[grp * 1536 + i];
    for (int i = tid; i < 3072; i += 512) red[i] = 0.f;
    __syncthreads();

    const int lane = tid & 63;
    const int wv   = tid >> 6;
    const int wnb  = (wv & 3) * 64;
    const int l16  = lane & 15;

    f32x4 acc[4][4];

    auto stats = [&](int RPB, int KOFF) {
        #pragma unroll
        for (int j = 0; j < 4; ++j) {
            int fl = wnb + j * 16 + l16;
            #pragma unroll
            for (int r = 0; r < 4; ++r) {
                float sr = 0.f, qr = 0.f;
                #pragma unroll
                for (int i = 0; i < 4; ++i) {
                    float v = acc[i][j][r];
                    sr += v; qr += v * v;
                }
                int kw = KOFF + (r & (RPB - 1));
                atomicAdd(&red[kw * 256 + fl], sr);
                atomicAdd(&red[1536 + kw * 256 + fl], qr);
            }
        }
    };

    #pragma unroll 1
    for (int s = 0; s < 2; ++s) {                   // G1: windows 0,1
        gemm_acc<512, 512, 0, 0>(embR, embV, W1b, Ash, Bsh, xsh, n_base, s * 64, 0, acc);
        stats(2, 0);
    }
    #pragma unroll 1
    for (int s = 0; s < 4; ++s) {                   // T full-win2: windows 2..5
        gemm_acc<1280, 1280, 0, 1>(embR, embV, W2b, Ash, Bsh, xsh, n_base, s * 32, 0, acc);
        stats(4, 2);
    }
    __syncthreads();
    for (int i = tid; i < 1536; i += 512) {
        int kw = i >> 8, f = n_base + (i & 255);
        atomicAdd(&accum[kw * 512 + f], red[i]);
        atomicAdd(&accum[3072 + kw * 512 + f], red[1536 + i]);
    }
}

// Pass B: per (128-batch, 256-f) block: G1-min -> LDS m1; H -> bf16 regs;
// 4x t_k -> running m2 = min relu(a_k(H+t_k)+c_k); final min/dot/reduce.
__global__ __launch_bounds__(512, 2)
void passB_kernel(const int* __restrict__ x, const bf16* __restrict__ embR,
                  const bf16* __restrict__ embV, const bf16* __restrict__ W1b,
                  const bf16* __restrict__ W2b, const float* __restrict__ coef,
                  const float* __restrict__ fcw, float* __restrict__ outacc)
{
    __shared__ __align__(16) short Ash[128 * 72];
    __shared__ __align__(16) short Bsh[256 * 72];
    __shared__ int xsh[128 * 12];
    __shared__ unsigned short m1s[128 * 256];

    const int tid = threadIdx.x;
    const int lin = blockIdx.x;
    const int grp = (lin >> 4) * 8 + (lin & 7);
    const int nt  = (lin >> 3) & 1;
    const int n_base = nt * 256;
    const int b0  = grp * 128;

    for (int i = tid; i < 1536; i += 512) xsh[i] = x[b0 * 12 + i];
    __syncthreads();

    const int lane = tid & 63;
    const int wv   = tid >> 6;
    const int wmb  = (wv >> 2) * 64;
    const int wnb  = (wv & 3) * 64;
    const int quad = lane >> 4;
    const int l16  = lane & 15;

    f32x4 acc[4][4];

    // ---- G1 -> m1 in LDS (bf16) ----
    #pragma unroll 1
    for (int s = 0; s < 2; ++s) {
        gemm_acc<512, 512, 0, 0>(embR, embV, W1b, Ash, Bsh, xsh, n_base, s * 64, 0, acc);
        #pragma unroll
        for (int j = 0; j < 4; ++j) {
            int fl = wnb + j * 16 + l16, f = n_base + fl;
            float a0 = coef[f],       c0 = coef[3072 + f];
            float a1 = coef[512 + f], c1 = coef[3584 + f];
            #pragma unroll
            for (int i = 0; i < 4; ++i)
                #pragma unroll
                for (int rp = 0; rp < 2; ++rp) {
                    int bl = s * 64 + ((wmb + i * 16 + quad * 4 + rp * 2) >> 1);
                    float v0 = fmaxf(a0 * acc[i][j][rp * 2]     + c0, 0.f);
                    float v1 = fmaxf(a1 * acc[i][j][rp * 2 + 1] + c1, 0.f);
                    m1s[bl * 256 + fl] = f2b(fminf(v0, v1));
                }
        }
    }

    // ---- H (K=768) -> packed bf16 regs ----
    gemm_acc<768, 1280, 0, 2>(embR, embV, W2b, Ash, Bsh, xsh, n_base, 0, 0, acc);
    unsigned hpk[4][4][2];
    #pragma unroll
    for (int i = 0; i < 4; ++i)
        #pragma unroll
        for (int j = 0; j < 4; ++j) {
            hpk[i][j][0] = (unsigned)f2b(acc[i][j][0]) | ((unsigned)f2b(acc[i][j][1]) << 16);
            hpk[i][j][1] = (unsigned)f2b(acc[i][j][2]) | ((unsigned)f2b(acc[i][j][3]) << 16);
        }

    // ---- t_k loop: running m2 ----
    f32x4 m2[4][4];
    #pragma unroll
    for (int i = 0; i < 4; ++i)
        #pragma unroll
        for (int j = 0; j < 4; ++j)
            m2[i][j] = (f32x4){1e30f, 1e30f, 1e30f, 1e30f};
    #pragma unroll 1
    for (int tk = 0; tk < 4; ++tk) {
        gemm_acc<512, 1280, 768, 3>(embR, embV, W2b, Ash, Bsh, xsh, n_base, 0, tk, acc);
        #pragma unroll
        for (int j = 0; j < 4; ++j) {
            int f = n_base + wnb + j * 16 + l16;
            float a = coef[(2 + tk) * 512 + f];
            float c = coef[3072 + (2 + tk) * 512 + f];
            #pragma unroll
            for (int i = 0; i < 4; ++i)
                #pragma unroll
                for (int r = 0; r < 4; ++r) {
                    unsigned u = hpk[i][j][r >> 1];
                    float h = b2f((unsigned short)((r & 1) ? (u >> 16) : (u & 0xffffu)));
                    float v = fmaxf(a * (acc[i][j][r] + h) + c, 0.f);
                    m2[i][j][r] = fminf(m2[i][j][r], v);
                }
        }
    }

    // ---- final: min(m1, m2) . fcw, reduce over l16, atomic ----
    float dotv[4][4];
    #pragma unroll
    for (int i = 0; i < 4; ++i)
        #pragma unroll
        for (int r = 0; r < 4; ++r) dotv[i][r] = 0.f;
    #pragma unroll
    for (int j = 0; j < 4; ++j) {
        int fl = wnb + j * 16 + l16;
        float fw = fcw[n_base + fl];
        #pragma unroll
        for (int i = 0; i < 4; ++i)
            #pragma unroll
            for (int r = 0; r < 4; ++r) {
                int bl = wmb + i * 16 + quad * 4 + r;
                float m1v = b2f(m1s[bl * 256 + fl]);
                dotv[i][r] += fminf(m1v, m2[i][j][r]) * fw;
            }
    }
    #pragma unroll
    for (int i = 0; i < 4; ++i)
        #pragma unroll
        for (int r = 0; r < 4; ++r) {
            float v = dotv[i][r];
            v += __shfl_xor(v, 1); v += __shfl_xor(v, 2);
            v += __shfl_xor(v, 4); v += __shfl_xor(v, 8);
            if (l16 == 0)
                atomicAdd(&outacc[b0 + wmb + i * 16 + quad * 4 + r], v);
        }
}

__global__ void bncoef_kernel(const float* __restrict__ accum,
                              const float* __restrict__ g1, const float* __restrict__ be1,
                              const float* __restrict__ g2, const float* __restrict__ be2,
                              float* __restrict__ coef)
{
    int id = blockIdx.x * 256 + threadIdx.x;
    if (id >= 3072) return;
    int kw = id >> 9, f = id & 511;
    float mean = accum[id] * (1.f / BATCH);
    float var  = accum[3072 + id] * (1.f / BATCH) - mean * mean;
    float g  = kw < 2 ? g1[f] : g2[f];
    float be = kw < 2 ? be1[f] : be2[f];
    float a  = g * rsqrtf(var + 1e-5f);
    coef[id] = a;
    coef[3072 + id] = be - a * mean;
}

__global__ void finish_kernel(const float* __restrict__ outacc,
                              const float* __restrict__ fcb, float* __restrict__ out)
{
    int b = blockIdx.x * 256 + threadIdx.x;
    if (b < BATCH)
        out[b] = outacc[b] + fcb[0];
}

extern "C" void kernel_launch(void* const* d_in, const int* in_sizes, int n_in,
                              void* d_out, int out_size, void* d_ws, size_t ws_size,
                              hipStream_t stream)
{
    (void)in_sizes; (void)n_in; (void)out_size; (void)ws_size;
    const int*   x    = (const int*)  d_in[0];
    const float* embR = (const float*)d_in[2];    // 50000 x 256 f32
    const float* embV = (const float*)d_in[3];    // 50000 x 256 f32
    const float* W1   = (const float*)d_in[4];    // 512 x 2 x 256 f32
    const float* g1   = (const float*)d_in[6];
    const float* be1  = (const float*)d_in[7];
    const float* W2   = (const float*)d_in[8];    // 512 x 5 x 256 f32
    const float* g2   = (const float*)d_in[10];
    const float* be2  = (const float*)d_in[11];
    const float* fcw  = (const float*)d_in[12];   // 512 f32
    const float* fcb  = (const float*)d_in[13];

    char* wsb = (char*)d_ws;
    float* accum  = (float*)wsb;                          //        0: 24 KB
    float* coef   = accum + 6144;                         //    24576: 24 KB
    float* outacc = coef + 6144;                          //    49152: 128 KB
    bf16*  Wbf1   = (bf16*)(wsb + 180224);                //   512 KB
    bf16*  Wbf2   = (bf16*)(wsb + 704512);                //  1.25 MB
    bf16*  embRb  = (bf16*)(wsb + 2015232);               //  25.6 MB
    bf16*  embVb  = (bf16*)(wsb + 27615232);              //  -> 53215232 (53.2MB)

    hipMemsetAsync(accum, 0, 6144 * sizeof(float), stream);
    hipMemsetAsync(outacc, 0, BATCH * sizeof(float), stream);
    cvt_kernel<<<256, 256, 0, stream>>>(W1, (unsigned short*)Wbf1, 65536);
    cvt_kernel<<<640, 256, 0, stream>>>(W2, (unsigned short*)Wbf2, 163840);
    cvt_kernel<<<12500, 256, 0, stream>>>(embR, (unsigned short*)embRb, 3200000);
    cvt_kernel<<<12500, 256, 0, stream>>>(embV, (unsigned short*)embVb, 3200000);

    passA_kernel<<<512, 512, 0, stream>>>(x, embRb, embVb, Wbf1, Wbf2, accum);
    bncoef_kernel<<<12, 256, 0, stream>>>(accum, g1, be1, g2, be2, coef);
    passB_kernel<<<512, 512, 0, stream>>>(x, embRb, embVb, Wbf1, Wbf2, coef, fcw, outacc);
    finish_kernel<<<128, 256, 0, stream>>>(outacc, fcb, (float*)d_out);
}